// Round 2
// 249.841 us; speedup vs baseline: 1.3619x; 1.3619x over previous
//
#include <hip/hip_runtime.h>
#include <hip/hip_bf16.h>
#include <stdint.h>

typedef __bf16 bf16x8 __attribute__((ext_vector_type(8)));
typedef float  f32x4  __attribute__((ext_vector_type(4)));
typedef unsigned short u16;
typedef unsigned int   u32;
typedef u16 u16x8 __attribute__((ext_vector_type(8)));

#define B_  32
#define N_  128
#define F_  128
#define G_  300
#define TAB_N 4096
#define TAB_SCALE 128.0f   // 1/delta ; table covers d in [0, 31.992]

__device__ __forceinline__ u16 f2b(float f){
  union { float f; u32 u; } x; x.f = f;
  u32 r = x.u + 0x7FFFu + ((x.u >> 16) & 1u);
  return (u16)(r >> 16);
}
// shifted softplus: log(0.5*exp(x)+0.5) = max(x,0) + log(0.5 + 0.5*exp(-|x|))
__device__ __forceinline__ float sspf(float x){
  return fmaxf(x, 0.0f) + __logf(0.5f + 0.5f*__expf(-fabsf(x)));
}
__device__ __forceinline__ f32x4 mfma16(bf16x8 a, bf16x8 b, f32x4 c){
  return __builtin_amdgcn_mfma_f32_16x16x32_bf16(a, b, c, 0, 0, 0);
}

// ---------------- setup: transpose+cast w_in2f to bf16 ----------------
__global__ __launch_bounds__(256) void k_setup(const float* __restrict__ w_in2f,
                                               u16* __restrict__ wi2t){
  int idx = blockIdx.x*256 + threadIdx.x;      // < 128*128
  int h = idx >> 7, ff = idx & 127;
  wi2t[idx] = f2b(w_in2f[ff*F_ + h]);          // wi2t[h][k] = w_in2f[k][h]
}

// ---------------- table generation: h(d) for d = t/128, t in [0,4096) ------
// h(d) = ssp(rbf(d) @ w_f1 + b_f1) @ w_f2 + b_f2   (all fp32, rounded once to bf16)
__global__ __launch_bounds__(256) void k_gentab(const float* __restrict__ w_f1,
                                                const float* __restrict__ b_f1,
                                                const float* __restrict__ w_f2,
                                                const float* __restrict__ b_f2,
                                                u16* __restrict__ tab){
  __shared__ float rbfs[16*301];
  __shared__ float ssa[16*132];
  int tid = threadIdx.x;
  int t0 = blockIdx.x * 16;                    // 256 blocks x 16 grid rows
  const float NG2LE = 14.4269504089f;          // gamma * log2(e) = 10*1.442695
  for (int v = tid; v < 16*G_; v += 256){
    int rr = v / G_;
    int k  = v - rr*G_;
    float d = (float)(t0 + rr) * (1.0f/TAB_SCALE);
    float c = (float)k * (30.0f/299.0f);
    float qd = d - c;
    rbfs[rr*301 + k] = __builtin_amdgcn_exp2f(-NG2LE * qd * qd);
  }
  __syncthreads();
  int rr = tid >> 4, h0 = (tid & 15)*8;
  float a1[8];
  #pragma unroll
  for (int t = 0; t < 8; ++t) a1[t] = b_f1[h0 + t];
  for (int k = 0; k < G_; ++k){
    float s = rbfs[rr*301 + k];
    float4 wa = *reinterpret_cast<const float4*>(w_f1 + k*F_ + h0);
    float4 wb = *reinterpret_cast<const float4*>(w_f1 + k*F_ + h0 + 4);
    a1[0] = fmaf(s, wa.x, a1[0]); a1[1] = fmaf(s, wa.y, a1[1]);
    a1[2] = fmaf(s, wa.z, a1[2]); a1[3] = fmaf(s, wa.w, a1[3]);
    a1[4] = fmaf(s, wb.x, a1[4]); a1[5] = fmaf(s, wb.y, a1[5]);
    a1[6] = fmaf(s, wb.z, a1[6]); a1[7] = fmaf(s, wb.w, a1[7]);
  }
  #pragma unroll
  for (int t = 0; t < 8; ++t) ssa[rr*132 + h0 + t] = sspf(a1[t]);
  __syncthreads();
  float a2[8];
  #pragma unroll
  for (int t = 0; t < 8; ++t) a2[t] = b_f2[h0 + t];
  for (int k = 0; k < F_; ++k){
    float s = ssa[rr*132 + k];
    float4 wa = *reinterpret_cast<const float4*>(w_f2 + k*F_ + h0);
    float4 wb = *reinterpret_cast<const float4*>(w_f2 + k*F_ + h0 + 4);
    a2[0] = fmaf(s, wa.x, a2[0]); a2[1] = fmaf(s, wa.y, a2[1]);
    a2[2] = fmaf(s, wa.z, a2[2]); a2[3] = fmaf(s, wa.w, a2[3]);
    a2[4] = fmaf(s, wb.x, a2[4]); a2[5] = fmaf(s, wb.y, a2[5]);
    a2[6] = fmaf(s, wb.z, a2[6]); a2[7] = fmaf(s, wb.w, a2[7]);
  }
  u16x8 ov;
  #pragma unroll
  for (int t = 0; t < 8; ++t) ov[t] = f2b(a2[t]);
  *reinterpret_cast<u16x8*>(tab + (size_t)(t0 + rr)*F_ + h0) = ov;
}

// ---------------- x = emb[z] (fp32 + bf16 copy) ----------------
__global__ __launch_bounds__(256) void k_embed(const int* __restrict__ z,
                                               const float* __restrict__ emb,
                                               float* __restrict__ x,
                                               u16* __restrict__ xb){
  int idx = blockIdx.x*256 + threadIdx.x;   // < 32*128*128
  int bn = idx >> 7, ff = idx & 127;
  float v = emb[z[bn]*F_ + ff];
  x[idx] = v;
  xb[idx] = f2b(v);
}

// ---------------- fused interaction: f-GEMM + table-cfconv + MLP + residual ----
// block = (b, 16-row i-tile); reads x_in/xb_in, writes x_out/xb_out (ping-pong).
__global__ __launch_bounds__(256) void k_fused(
    const float* __restrict__ x_in, const u16* __restrict__ xb_in,
    const u16* __restrict__ wi2t,  const u16* __restrict__ tab,
    const float* __restrict__ r,
    const float* __restrict__ w_f2out, const float* __restrict__ b_f2out,
    const float* __restrict__ w_out,   const float* __restrict__ b_out,
    float* __restrict__ x_out, u16* __restrict__ xb_out){
  __shared__ __attribute__((aligned(16))) float fsh[128][132];   // f = x@w_in2f
  __shared__ float rsh[128][4];
  __shared__ u32   dIdxS[2048];
  __shared__ float dFracS[2048];
  __shared__ float ysh[16][132];
  int b = blockIdx.x >> 3, i0 = (blockIdx.x & 7)*16;
  int tid = threadIdx.x, lane = tid & 63, wave = tid >> 6;
  int m = lane & 15, q = lane >> 4;

  if (tid < 128){
    const float* rp = r + (size_t)(b*N_ + tid)*3;
    rsh[tid][0] = rp[0]; rsh[tid][1] = rp[1]; rsh[tid][2] = rp[2];
  }
  __syncthreads();

  // ---- f = x @ w_in2f via bf16 MFMA; each wave owns a 64x64 quadrant ----
  int jr = (wave >> 1)*64, kc = (wave & 1)*64;
  f32x4 acc[4][4];
  #pragma unroll
  for (int mi = 0; mi < 4; ++mi)
    #pragma unroll
    for (int ni = 0; ni < 4; ++ni) acc[mi][ni] = (f32x4){0.f,0.f,0.f,0.f};
  const u16* xbb = xb_in + (size_t)b*N_*F_;
  #pragma unroll
  for (int ks = 0; ks < 4; ++ks){
    int k0 = ks*32 + q*8;
    bf16x8 af[4], bfv[4];
    #pragma unroll
    for (int mi = 0; mi < 4; ++mi)
      af[mi] = *reinterpret_cast<const bf16x8*>(xbb + (jr + mi*16 + m)*F_ + k0);
    #pragma unroll
    for (int ni = 0; ni < 4; ++ni)
      bfv[ni] = *reinterpret_cast<const bf16x8*>(wi2t + (kc + ni*16 + m)*F_ + k0);
    #pragma unroll
    for (int mi = 0; mi < 4; ++mi)
      #pragma unroll
      for (int ni = 0; ni < 4; ++ni)
        acc[mi][ni] = mfma16(af[mi], bfv[ni], acc[mi][ni]);
  }

  // ---- per-pair table index/frac (overlaps MFMA latency) ----
  #pragma unroll
  for (int t = 0; t < 8; ++t){
    int p = tid + t*256;                 // 2048 pairs: (il, j)
    int il = p >> 7, j = p & 127;
    float dx = rsh[i0+il][0] - rsh[j][0];
    float dy = rsh[i0+il][1] - rsh[j][1];
    float dz = rsh[i0+il][2] - rsh[j][2];
    float d = sqrtf(fmaf(dx,dx, fmaf(dy,dy, fmaf(dz,dz, 1e-12f))));
    float u = fminf(d * TAB_SCALE, (float)(TAB_N - 1));
    int ix = (int)u; if (ix > TAB_N - 2) ix = TAB_N - 2;
    dIdxS[p]  = (u32)ix;
    dFracS[p] = u - (float)ix;
  }

  #pragma unroll
  for (int mi = 0; mi < 4; ++mi)
    #pragma unroll
    for (int ni = 0; ni < 4; ++ni)
      #pragma unroll
      for (int rr = 0; rr < 4; ++rr)
        fsh[jr + mi*16 + q*4 + rr][kc + ni*16 + m] = acc[mi][ni][rr];
  __syncthreads();

  // ---- cfconv: y[i,h] = sum_j lerp(tab, d_ij)[h] * f[j,h] ----
  int il = tid >> 4, h0 = (tid & 15)*8;
  float y[8] = {0,0,0,0,0,0,0,0};
  const u16* tbp = tab + h0;
  const u32* dIp = dIdxS + il*128;
  const float* dFp = dFracS + il*128;
  #pragma unroll 4
  for (int j = 0; j < 128; ++j){
    u32 ix = dIp[j];
    float fr = dFp[j];
    const u16* rp = tbp + (ix << 7);
    bf16x8 ta  = *reinterpret_cast<const bf16x8*>(rp);
    bf16x8 tb2 = *reinterpret_cast<const bf16x8*>(rp + F_);
    float fv[8];
    *reinterpret_cast<float4*>(&fv[0]) = *reinterpret_cast<const float4*>(&fsh[j][h0]);
    *reinterpret_cast<float4*>(&fv[4]) = *reinterpret_cast<const float4*>(&fsh[j][h0+4]);
    #pragma unroll
    for (int t = 0; t < 8; ++t){
      float a = (float)ta[t];
      float cd = (float)tb2[t] - a;
      y[t] = fmaf(fmaf(fr, cd, a), fv[t], y[t]);
    }
  }
  #pragma unroll
  for (int t = 0; t < 8; ++t) ysh[il][h0 + t] = y[t];
  __syncthreads();

  // ---- y2 = ssp(y @ w_f2out + b_f2out)  (fp32 weights, exact) ----
  float y2[8] = {0,0,0,0,0,0,0,0};
  for (int k = 0; k < 128; ++k){
    float yv = ysh[il][k];
    float4 wa = *reinterpret_cast<const float4*>(w_f2out + k*F_ + h0);
    float4 wb = *reinterpret_cast<const float4*>(w_f2out + k*F_ + h0 + 4);
    y2[0] = fmaf(yv, wa.x, y2[0]); y2[1] = fmaf(yv, wa.y, y2[1]);
    y2[2] = fmaf(yv, wa.z, y2[2]); y2[3] = fmaf(yv, wa.w, y2[3]);
    y2[4] = fmaf(yv, wb.x, y2[4]); y2[5] = fmaf(yv, wb.y, y2[5]);
    y2[6] = fmaf(yv, wb.z, y2[6]); y2[7] = fmaf(yv, wb.w, y2[7]);
  }
  #pragma unroll
  for (int t = 0; t < 8; ++t) y2[t] = sspf(y2[t] + b_f2out[h0 + t]);
  __syncthreads();
  #pragma unroll
  for (int t = 0; t < 8; ++t) ysh[il][h0 + t] = y2[t];
  __syncthreads();

  // ---- v = y2 @ w_out + b_out ; x_out = x_in + v (ping-pong, race-free) ----
  float v2[8] = {0,0,0,0,0,0,0,0};
  for (int k = 0; k < 128; ++k){
    float yv = ysh[il][k];
    float4 wa = *reinterpret_cast<const float4*>(w_out + k*F_ + h0);
    float4 wb = *reinterpret_cast<const float4*>(w_out + k*F_ + h0 + 4);
    v2[0] = fmaf(yv, wa.x, v2[0]); v2[1] = fmaf(yv, wa.y, v2[1]);
    v2[2] = fmaf(yv, wa.z, v2[2]); v2[3] = fmaf(yv, wa.w, v2[3]);
    v2[4] = fmaf(yv, wb.x, v2[4]); v2[5] = fmaf(yv, wb.y, v2[5]);
    v2[6] = fmaf(yv, wb.z, v2[6]); v2[7] = fmaf(yv, wb.w, v2[7]);
  }
  size_t ro = ((size_t)b*N_ + i0 + il)*F_ + h0;
  const float* xi = x_in + ro;
  float nv[8]; u16x8 bv;
  #pragma unroll
  for (int t = 0; t < 8; ++t){
    float t2 = xi[t] + v2[t] + b_out[h0 + t];
    nv[t] = t2; bv[t] = f2b(t2);
  }
  *reinterpret_cast<float4*>(x_out + ro)     = *reinterpret_cast<float4*>(&nv[0]);
  *reinterpret_cast<float4*>(x_out + ro + 4) = *reinterpret_cast<float4*>(&nv[4]);
  *reinterpret_cast<u16x8*>(xb_out + ro) = bv;
}

// ---------------- readout: out = ssp(x@w_aw1+b)@w_aw2 + b2 ----------------
__global__ __launch_bounds__(256) void k_readout(const float* __restrict__ x,
                                                 const float* __restrict__ w_aw1,
                                                 const float* __restrict__ b_aw1,
                                                 const float* __restrict__ w_aw2,
                                                 const float* __restrict__ b_aw2,
                                                 float* __restrict__ out){
  int tid = threadIdx.x, lane = tid & 63, wave = tid >> 6;
  int atom = blockIdx.x*4 + wave;           // < 4096
  const float* xr = x + (size_t)atom*F_;
  float a0 = 0.f, a1 = 0.f;
  int f0 = lane, f1 = lane + 64;
  for (int k = 0; k < 128; ++k){
    float xv = xr[k];
    a0 += xv*w_aw1[k*F_ + f0];
    a1 += xv*w_aw1[k*F_ + f1];
  }
  float h0 = sspf(a0 + b_aw1[f0]);
  float h1 = sspf(a1 + b_aw1[f1]);
  float s = h0*w_aw2[f0] + h1*w_aw2[f1];
  #pragma unroll
  for (int off = 32; off; off >>= 1) s += __shfl_down(s, off, 64);
  if (lane == 0) out[atom] = s + b_aw2[0];
}

extern "C" void kernel_launch(void* const* d_in, const int* in_sizes, int n_in,
                              void* d_out, int out_size, void* d_ws, size_t ws_size,
                              hipStream_t stream){
  const int*   z       = (const int*)d_in[0];
  const float* r       = (const float*)d_in[1];
  const float* emb     = (const float*)d_in[2];
  const float* w_in2f  = (const float*)d_in[3];
  const float* w_f1    = (const float*)d_in[4];
  const float* b_f1    = (const float*)d_in[5];
  const float* w_f2    = (const float*)d_in[6];
  const float* b_f2    = (const float*)d_in[7];
  const float* w_f2out = (const float*)d_in[8];
  const float* b_f2out = (const float*)d_in[9];
  const float* w_out   = (const float*)d_in[10];
  const float* b_out   = (const float*)d_in[11];
  const float* w_aw1   = (const float*)d_in[12];
  const float* b_aw1   = (const float*)d_in[13];
  const float* w_aw2   = (const float*)d_in[14];
  const float* b_aw2   = (const float*)d_in[15];

  // workspace layout (7.4 MB total)
  char* ws = (char*)d_ws;
  float* x0   = (float*)(ws);                        // 2,097,152
  float* x1   = (float*)(ws + 2097152);              // 2,097,152
  u16*   xb0  = (u16*)(ws + 4194304);                // 1,048,576
  u16*   xb1  = (u16*)(ws + 5242880);                // 1,048,576
  u16*   tab  = (u16*)(ws + 6291456);                // 1,048,576
  u16*   wi2t = (u16*)(ws + 7340032);                //    32,768

  k_setup<<<64, 256, 0, stream>>>(w_in2f, wi2t);
  k_gentab<<<256, 256, 0, stream>>>(w_f1, b_f1, w_f2, b_f2, tab);
  k_embed<<<2048, 256, 0, stream>>>(z, emb, x0, xb0);
  k_fused<<<256, 256, 0, stream>>>(x0, xb0, wi2t, tab, r,
                                   w_f2out, b_f2out, w_out, b_out, x1, xb1);
  k_fused<<<256, 256, 0, stream>>>(x1, xb1, wi2t, tab, r,
                                   w_f2out, b_f2out, w_out, b_out, x0, xb0);
  k_fused<<<256, 256, 0, stream>>>(x0, xb0, wi2t, tab, r,
                                   w_f2out, b_f2out, w_out, b_out, x1, xb1);
  k_readout<<<1024, 256, 0, stream>>>(x1, w_aw1, b_aw1, w_aw2, b_aw2, (float*)d_out);
}